// Round 1
// baseline (89.325 us; speedup 1.0000x reference)
//
#include <hip/hip_runtime.h>
#include <hip/hip_bf16.h>

// Problem constants (fixed by reference file)
#define NN 1024   // rows
#define HH 512    // inner dim
#define OO 512    // output dim
// NUM_PARAMS = 4, ORDER = 3 (order/msg_to read from device scalars at runtime)

typedef __attribute__((ext_vector_type(4))) float f32x4;
typedef __attribute__((ext_vector_type(8))) unsigned short u16x8;

__device__ __forceinline__ unsigned short f2bf(float f) {
  __hip_bfloat16 h = __float2bfloat16(f);   // RNE
  return __builtin_bit_cast(unsigned short, h);
}

// ---------------------------------------------------------------------------
// Kernel 1: prep.
//   blocks [0,256):   FP[n][h] = prod_{i != msg_to} inp[i][n][h]  -> bf16
//   blocks [256,512): Bt[p][o][h] = bf16(params[p][h][o])  (LDS-tiled transpose)
// ---------------------------------------------------------------------------
__global__ __launch_bounds__(256) void prep_kernel(
    const float* __restrict__ inp, const float* __restrict__ params,
    const int* __restrict__ msg_to_p, const int* __restrict__ order_p,
    unsigned short* __restrict__ FPbf, unsigned short* __restrict__ Btbf)
{
  const int tid = threadIdx.x;
  const int bx  = blockIdx.x;
  const int msg_to = msg_to_p[0];
  const int order  = order_p[0];
  __shared__ unsigned short tile[64][72];   // transpose staging (pad vs bank conflicts)

  if (bx < 256) {
    // ---- FP part: 256 blocks * 256 threads * 8 elems = 524288 = N*H
    size_t off = ((size_t)bx * 256 + tid) * 8;
    float pr[8] = {1.f,1.f,1.f,1.f,1.f,1.f,1.f,1.f};
    for (int i = 0; i < order; ++i) {
      if (i == msg_to) continue;
      const float4* s4 = reinterpret_cast<const float4*>(inp + (size_t)i*NN*HH + off);
      float4 x0 = s4[0], x1 = s4[1];
      pr[0]*=x0.x; pr[1]*=x0.y; pr[2]*=x0.z; pr[3]*=x0.w;
      pr[4]*=x1.x; pr[5]*=x1.y; pr[6]*=x1.z; pr[7]*=x1.w;
    }
    u16x8 u;
#pragma unroll
    for (int j = 0; j < 8; ++j) u[j] = f2bf(pr[j]);
    *reinterpret_cast<u16x8*>(FPbf + off) = u;
  } else {
    // ---- transpose part: 256 blocks = 4 p * 8 h-tiles * 8 o-tiles (64x64 tiles)
    int t  = bx - 256;
    int p  = t >> 6;
    int t6 = t & 63;
    int h0 = (t6 >> 3) << 6;
    int o0 = (t6 & 7) << 6;
    const float* src = params + ((size_t)p*HH + h0)*OO + o0;
#pragma unroll
    for (int q = 0; q < 4; ++q) {
      int idx = q*256 + tid;          // 0..1023
      int r   = idx >> 4;             // h row 0..63
      int c4  = (idx & 15) * 4;       // o col 0..60
      float4 v = *reinterpret_cast<const float4*>(src + r*OO + c4);
      tile[r][c4+0] = f2bf(v.x); tile[r][c4+1] = f2bf(v.y);
      tile[r][c4+2] = f2bf(v.z); tile[r][c4+3] = f2bf(v.w);
    }
    __syncthreads();
    unsigned short* dst = Btbf + ((size_t)p*OO + o0)*HH + h0;
#pragma unroll
    for (int q = 0; q < 2; ++q) {
      int slot = q*256 + tid;         // 0..511
      int ol   = slot >> 3;           // o local 0..63
      int h8   = (slot & 7) * 8;      // h octet base
      u16x8 u;
#pragma unroll
      for (int j = 0; j < 8; ++j) u[j] = tile[h8+j][ol];
      *reinterpret_cast<u16x8*>(dst + (size_t)ol*HH + h8) = u;
    }
  }
}

// ---------------------------------------------------------------------------
// Kernel 2: bf16 MFMA GEMM, 128x128 tile, 4 waves (2x2 of 64x64), BK=32.
// grid = (N/128, O/128, 4 params). Block p writes only rows with id==p,
// bias fused in epilogue.
// ---------------------------------------------------------------------------
__global__ __launch_bounds__(256) void gemm_kernel(
    const unsigned short* __restrict__ FPbf,   // [N][H] bf16
    const unsigned short* __restrict__ Btbf,   // [4][O][H] bf16
    const float* __restrict__ bias,            // [4][O]
    const int* __restrict__ edge_types,        // [N][order]
    const int* __restrict__ msg_to_p, const int* __restrict__ order_p,
    float* __restrict__ out)                   // [N][O]
{
  __shared__ __align__(16) unsigned short Ash[128][40];  // pad 32->40: no 8-way conflict
  __shared__ __align__(16) unsigned short Bsh[128][40];
  const int tid  = threadIdx.x;
  const int lane = tid & 63;
  const int wave = tid >> 6;
  const int wr = wave >> 1, wc = wave & 1;
  const int m0 = blockIdx.x * 128, o0 = blockIdx.y * 128;
  const int p  = blockIdx.z;
  const int msg_to = msg_to_p[0];
  const int order  = order_p[0];

  f32x4 acc[4][4];
#pragma unroll
  for (int i = 0; i < 4; ++i)
#pragma unroll
    for (int j = 0; j < 4; ++j) acc[i][j] = (f32x4){0.f, 0.f, 0.f, 0.f};

  const int l15 = lane & 15;
  const int lk0 = (lane >> 4) * 8;   // k-octet base for A/B fragments

  for (int kt = 0; kt < HH; kt += 32) {
    // stage A (128x32) and B^T (128x32) tiles; 256 thr * 2 chunks of 8 bf16 each
#pragma unroll
    for (int c = 0; c < 2; ++c) {
      int idx = c*256 + tid;
      int row = idx >> 2;            // 0..127
      int k0  = (idx & 3) * 8;       // 0,8,16,24
      u16x8 va = *reinterpret_cast<const u16x8*>(FPbf + (size_t)(m0+row)*HH + kt + k0);
      *reinterpret_cast<u16x8*>(&Ash[row][k0]) = va;
      u16x8 vb = *reinterpret_cast<const u16x8*>(Btbf + ((size_t)p*OO + o0 + row)*HH + kt + k0);
      *reinterpret_cast<u16x8*>(&Bsh[row][k0]) = vb;
    }
    __syncthreads();

    u16x8 aF[4], bF[4];
#pragma unroll
    for (int mi = 0; mi < 4; ++mi)
      aF[mi] = *reinterpret_cast<const u16x8*>(&Ash[wr*64 + mi*16 + l15][lk0]);
#pragma unroll
    for (int ni = 0; ni < 4; ++ni)
      bF[ni] = *reinterpret_cast<const u16x8*>(&Bsh[wc*64 + ni*16 + l15][lk0]);

#pragma unroll
    for (int mi = 0; mi < 4; ++mi)
#pragma unroll
      for (int ni = 0; ni < 4; ++ni)
        asm("v_mfma_f32_16x16x32_bf16 %0, %1, %2, %0"
            : "+v"(acc[mi][ni]) : "v"(aF[mi]), "v"(bF[ni]));

    __syncthreads();
  }

  asm volatile("s_nop 7\n\ts_nop 7" ::: "memory");  // MFMA->VALU hazard insurance

  // epilogue: C/D layout col=lane&15, row=(lane>>4)*4+reg
#pragma unroll
  for (int mi = 0; mi < 4; ++mi) {
#pragma unroll
    for (int r = 0; r < 4; ++r) {
      int n  = m0 + wr*64 + mi*16 + (lane >> 4)*4 + r;
      int id = edge_types[n*order + msg_to];
      if (id != p) continue;
      const int ob = o0 + wc*64 + l15;
#pragma unroll
      for (int ni = 0; ni < 4; ++ni) {
        int o = ob + ni*16;
        out[(size_t)n*OO + o] = acc[mi][ni][r] + bias[p*OO + o];
      }
    }
  }
}

extern "C" void kernel_launch(void* const* d_in, const int* in_sizes, int n_in,
                              void* d_out, int out_size, void* d_ws, size_t ws_size,
                              hipStream_t stream) {
  const float* inp        = (const float*)d_in[0];
  const float* params     = (const float*)d_in[1];
  const float* bias       = (const float*)d_in[2];
  const int*   edge_types = (const int*)d_in[3];
  // d_in[4]=atoms, d_in[5]=atom_edges unused by reference
  const int*   msg_to_p   = (const int*)d_in[6];
  const int*   order_p    = (const int*)d_in[7];
  float* out = (float*)d_out;

  unsigned short* FPbf = (unsigned short*)d_ws;            // N*H bf16 = 1 MB
  unsigned short* Btbf = FPbf + (size_t)NN*HH;             // 4*O*H bf16 = 2 MB

  prep_kernel<<<512, 256, 0, stream>>>(inp, params, msg_to_p, order_p, FPbf, Btbf);
  gemm_kernel<<<dim3(8, 4, 4), 256, 0, stream>>>(FPbf, Btbf, bias, edge_types,
                                                 msg_to_p, order_p, out);
}

// Round 7
// 85.723 us; speedup vs baseline: 1.0420x; 1.0420x over previous
//
#include <hip/hip_runtime.h>
#include <hip/hip_bf16.h>

// Problem constants (fixed by reference file)
#define NN 1024   // rows
#define HH 512    // inner dim
#define OO 512    // output dim
// NUM_PARAMS = 4, ORDER = 3 (order/msg_to read from device scalars at runtime)

#define BM 128
#define BO 64
#define BK 64
#define LPAD 72   // row stride 144B == 16 mod 32 -> <=4-way ds_read aliasing

typedef __attribute__((ext_vector_type(4))) float f32x4;
typedef __attribute__((ext_vector_type(8))) unsigned short u16x8;

__device__ __forceinline__ unsigned short f2bf(float f) {
  __hip_bfloat16 h = __float2bfloat16(f);   // RNE
  return __builtin_bit_cast(unsigned short, h);
}

// ---------------------------------------------------------------------------
// Kernel 1: prep.  (unchanged from the passing round-0 version)
//   blocks [0,256):   FP[n][h] = prod_{i != msg_to} inp[i][n][h]  -> bf16
//   blocks [256,512): Bt[p][o][h] = bf16(params[p][h][o])  (LDS-tiled transpose)
// ---------------------------------------------------------------------------
__global__ __launch_bounds__(256) void prep_kernel(
    const float* __restrict__ inp, const float* __restrict__ params,
    const int* __restrict__ msg_to_p, const int* __restrict__ order_p,
    unsigned short* __restrict__ FPbf, unsigned short* __restrict__ Btbf)
{
  const int tid = threadIdx.x;
  const int bx  = blockIdx.x;
  const int msg_to = msg_to_p[0];
  const int order  = order_p[0];
  __shared__ unsigned short tile[64][72];   // transpose staging (pad vs bank conflicts)

  if (bx < 256) {
    // ---- FP part: 256 blocks * 256 threads * 8 elems = 524288 = N*H
    size_t off = ((size_t)bx * 256 + tid) * 8;
    float pr[8] = {1.f,1.f,1.f,1.f,1.f,1.f,1.f,1.f};
    for (int i = 0; i < order; ++i) {
      if (i == msg_to) continue;
      const float4* s4 = reinterpret_cast<const float4*>(inp + (size_t)i*NN*HH + off);
      float4 x0 = s4[0], x1 = s4[1];
      pr[0]*=x0.x; pr[1]*=x0.y; pr[2]*=x0.z; pr[3]*=x0.w;
      pr[4]*=x1.x; pr[5]*=x1.y; pr[6]*=x1.z; pr[7]*=x1.w;
    }
    u16x8 u;
#pragma unroll
    for (int j = 0; j < 8; ++j) u[j] = f2bf(pr[j]);
    *reinterpret_cast<u16x8*>(FPbf + off) = u;
  } else {
    // ---- transpose part: 256 blocks = 4 p * 8 h-tiles * 8 o-tiles (64x64 tiles)
    int t  = bx - 256;
    int p  = t >> 6;
    int t6 = t & 63;
    int h0 = (t6 >> 3) << 6;
    int o0 = (t6 & 7) << 6;
    const float* src = params + ((size_t)p*HH + h0)*OO + o0;
#pragma unroll
    for (int q = 0; q < 4; ++q) {
      int idx = q*256 + tid;          // 0..1023
      int r   = idx >> 4;             // h row 0..63
      int c4  = (idx & 15) * 4;       // o col 0..60
      float4 v = *reinterpret_cast<const float4*>(src + r*OO + c4);
      tile[r][c4+0] = f2bf(v.x); tile[r][c4+1] = f2bf(v.y);
      tile[r][c4+2] = f2bf(v.z); tile[r][c4+3] = f2bf(v.w);
    }
    __syncthreads();
    unsigned short* dst = Btbf + ((size_t)p*OO + o0)*HH + h0;
#pragma unroll
    for (int q = 0; q < 2; ++q) {
      int slot = q*256 + tid;         // 0..511
      int ol   = slot >> 3;           // o local 0..63
      int h8   = (slot & 7) * 8;      // h octet base
      u16x8 u;
#pragma unroll
      for (int j = 0; j < 8; ++j) u[j] = tile[h8+j][ol];
      *reinterpret_cast<u16x8*>(dst + (size_t)ol*HH + h8) = u;
    }
  }
}

// ---------------------------------------------------------------------------
// Kernel 2: bf16 MFMA GEMM — round-0 verified template (single-buffered,
// stage -> sync -> frag-reads+MFMA -> sync), parameter changes only:
// BM=128, BO=64, BK=64 (kk-unroll inside the barrier pair).
// grid = (8, 8, 4) = 256 blocks -> 1 block/CU.
// Block p writes only rows with edge id == p; bias fused in epilogue.
// ---------------------------------------------------------------------------
__global__ __launch_bounds__(256) void gemm_kernel(
    const unsigned short* __restrict__ FPbf,   // [N][H] bf16
    const unsigned short* __restrict__ Btbf,   // [4][O][H] bf16
    const float* __restrict__ bias,            // [4][O]
    const int* __restrict__ edge_types,        // [N][order]
    const int* __restrict__ msg_to_p, const int* __restrict__ order_p,
    float* __restrict__ out)                   // [N][O]
{
  __shared__ __align__(16) unsigned short Ash[BM][LPAD];
  __shared__ __align__(16) unsigned short Bsh[BO][LPAD];
  const int tid  = threadIdx.x;
  const int lane = tid & 63;
  const int wave = tid >> 6;
  const int wr = wave >> 1, wc = wave & 1;   // 2x2 wave grid: 64-row x 32-col strips
  const int m0 = blockIdx.x * BM, o0 = blockIdx.y * BO;
  const int p  = blockIdx.z;
  const int msg_to = msg_to_p[0];
  const int order  = order_p[0];

  f32x4 acc[4][2];
#pragma unroll
  for (int i = 0; i < 4; ++i)
#pragma unroll
    for (int j = 0; j < 2; ++j) acc[i][j] = (f32x4){0.f, 0.f, 0.f, 0.f};

  const int l15 = lane & 15;
  const int lk0 = (lane >> 4) * 8;   // k-octet base within a 32-wide k-slice

  for (int kt = 0; kt < HH; kt += BK) {
    // stage A (128x64) and B^T (64x64): 256 thr, 4 + 2 chunks of 8 bf16
#pragma unroll
    for (int c = 0; c < 4; ++c) {
      int idx = c*256 + tid; int row = idx >> 3; int k8 = (idx & 7) * 8;
      u16x8 va = *reinterpret_cast<const u16x8*>(FPbf + (size_t)(m0+row)*HH + kt + k8);
      *reinterpret_cast<u16x8*>(&Ash[row][k8]) = va;
    }
#pragma unroll
    for (int c = 0; c < 2; ++c) {
      int idx = c*256 + tid; int row = idx >> 3; int k8 = (idx & 7) * 8;
      u16x8 vb = *reinterpret_cast<const u16x8*>(Btbf + ((size_t)p*OO + o0 + row)*HH + kt + k8);
      *reinterpret_cast<u16x8*>(&Bsh[row][k8]) = vb;
    }
    __syncthreads();

#pragma unroll
    for (int kk = 0; kk < 2; ++kk) {
      u16x8 bF0 = *reinterpret_cast<const u16x8*>(&Bsh[wc*32 +  0 + l15][kk*32 + lk0]);
      u16x8 bF1 = *reinterpret_cast<const u16x8*>(&Bsh[wc*32 + 16 + l15][kk*32 + lk0]);
      u16x8 aF[4];
#pragma unroll
      for (int mi = 0; mi < 4; ++mi)
        aF[mi] = *reinterpret_cast<const u16x8*>(&Ash[wr*64 + mi*16 + l15][kk*32 + lk0]);
#pragma unroll
      for (int mi = 0; mi < 4; ++mi) {
        asm("v_mfma_f32_16x16x32_bf16 %0, %1, %2, %0"
            : "+v"(acc[mi][0]) : "v"(aF[mi]), "v"(bF0));
        asm("v_mfma_f32_16x16x32_bf16 %0, %1, %2, %0"
            : "+v"(acc[mi][1]) : "v"(aF[mi]), "v"(bF1));
      }
    }

    __syncthreads();
  }

  asm volatile("s_nop 7\n\ts_nop 7" ::: "memory");  // MFMA->VALU hazard insurance

  // epilogue: C/D layout col=lane&15, row=(lane>>4)*4+reg
#pragma unroll
  for (int mi = 0; mi < 4; ++mi) {
#pragma unroll
    for (int r = 0; r < 4; ++r) {
      int n  = m0 + wr*64 + mi*16 + (lane >> 4)*4 + r;
      int id = edge_types[n*order + msg_to];
      if (id != p) continue;
      const int ob = o0 + wc*32 + l15;
#pragma unroll
      for (int ni = 0; ni < 2; ++ni) {
        int o = ob + ni*16;
        out[(size_t)n*OO + o] = acc[mi][ni][r] + bias[p*OO + o];
      }
    }
  }
}

extern "C" void kernel_launch(void* const* d_in, const int* in_sizes, int n_in,
                              void* d_out, int out_size, void* d_ws, size_t ws_size,
                              hipStream_t stream) {
  const float* inp        = (const float*)d_in[0];
  const float* params     = (const float*)d_in[1];
  const float* bias       = (const float*)d_in[2];
  const int*   edge_types = (const int*)d_in[3];
  // d_in[4]=atoms, d_in[5]=atom_edges unused by reference
  const int*   msg_to_p   = (const int*)d_in[6];
  const int*   order_p    = (const int*)d_in[7];
  float* out = (float*)d_out;

  unsigned short* FPbf = (unsigned short*)d_ws;            // N*H bf16 = 1 MB
  unsigned short* Btbf = FPbf + (size_t)NN*HH;             // 4*O*H bf16 = 2 MB

  prep_kernel<<<512, 256, 0, stream>>>(inp, params, msg_to_p, order_p, FPbf, Btbf);
  gemm_kernel<<<dim3(NN/BM, OO/BO, 4), 256, 0, stream>>>(FPbf, Btbf, bias, edge_types,
                                                         msg_to_p, order_p, out);
}

// Round 8
// 84.033 us; speedup vs baseline: 1.0630x; 1.0201x over previous
//
#include <hip/hip_runtime.h>
#include <hip/hip_bf16.h>

// Problem constants (fixed by reference file)
#define NN 1024   // rows
#define HH 512    // inner dim
#define OO 512    // output dim
// NUM_PARAMS = 4, ORDER = 3 (order/msg_to read from device scalars at runtime)

#define BM 128
#define BO 64
#define BK 128    // 4 k-iterations (was 8): halves barrier/latency count
#define LPAD 136  // row stride 272B: 68 dwords == 4 mod 32 -> balanced, same class as 72

typedef __attribute__((ext_vector_type(4))) float f32x4;
typedef __attribute__((ext_vector_type(8))) unsigned short u16x8;

__device__ __forceinline__ unsigned short f2bf(float f) {
  __hip_bfloat16 h = __float2bfloat16(f);   // RNE
  return __builtin_bit_cast(unsigned short, h);
}

// ---------------------------------------------------------------------------
// Kernel 1: prep.  (unchanged from the passing round-0 version)
//   blocks [0,256):   FP[n][h] = prod_{i != msg_to} inp[i][n][h]  -> bf16
//   blocks [256,512): Bt[p][o][h] = bf16(params[p][h][o])  (LDS-tiled transpose)
// ---------------------------------------------------------------------------
__global__ __launch_bounds__(256) void prep_kernel(
    const float* __restrict__ inp, const float* __restrict__ params,
    const int* __restrict__ msg_to_p, const int* __restrict__ order_p,
    unsigned short* __restrict__ FPbf, unsigned short* __restrict__ Btbf)
{
  const int tid = threadIdx.x;
  const int bx  = blockIdx.x;
  const int msg_to = msg_to_p[0];
  const int order  = order_p[0];
  __shared__ unsigned short tile[64][72];   // transpose staging (pad vs bank conflicts)

  if (bx < 256) {
    // ---- FP part: 256 blocks * 256 threads * 8 elems = 524288 = N*H
    size_t off = ((size_t)bx * 256 + tid) * 8;
    float pr[8] = {1.f,1.f,1.f,1.f,1.f,1.f,1.f,1.f};
    for (int i = 0; i < order; ++i) {
      if (i == msg_to) continue;
      const float4* s4 = reinterpret_cast<const float4*>(inp + (size_t)i*NN*HH + off);
      float4 x0 = s4[0], x1 = s4[1];
      pr[0]*=x0.x; pr[1]*=x0.y; pr[2]*=x0.z; pr[3]*=x0.w;
      pr[4]*=x1.x; pr[5]*=x1.y; pr[6]*=x1.z; pr[7]*=x1.w;
    }
    u16x8 u;
#pragma unroll
    for (int j = 0; j < 8; ++j) u[j] = f2bf(pr[j]);
    *reinterpret_cast<u16x8*>(FPbf + off) = u;
  } else {
    // ---- transpose part: 256 blocks = 4 p * 8 h-tiles * 8 o-tiles (64x64 tiles)
    int t  = bx - 256;
    int p  = t >> 6;
    int t6 = t & 63;
    int h0 = (t6 >> 3) << 6;
    int o0 = (t6 & 7) << 6;
    const float* src = params + ((size_t)p*HH + h0)*OO + o0;
#pragma unroll
    for (int q = 0; q < 4; ++q) {
      int idx = q*256 + tid;          // 0..1023
      int r   = idx >> 4;             // h row 0..63
      int c4  = (idx & 15) * 4;       // o col 0..60
      float4 v = *reinterpret_cast<const float4*>(src + r*OO + c4);
      tile[r][c4+0] = f2bf(v.x); tile[r][c4+1] = f2bf(v.y);
      tile[r][c4+2] = f2bf(v.z); tile[r][c4+3] = f2bf(v.w);
    }
    __syncthreads();
    unsigned short* dst = Btbf + ((size_t)p*OO + o0)*HH + h0;
#pragma unroll
    for (int q = 0; q < 2; ++q) {
      int slot = q*256 + tid;         // 0..511
      int ol   = slot >> 3;           // o local 0..63
      int h8   = (slot & 7) * 8;      // h octet base
      u16x8 u;
#pragma unroll
      for (int j = 0; j < 8; ++j) u[j] = tile[h8+j][ol];
      *reinterpret_cast<u16x8*>(dst + (size_t)ol*HH + h8) = u;
    }
  }
}

// ---------------------------------------------------------------------------
// Kernel 2: bf16 MFMA GEMM — round-0 verified template (single-buffered,
// stage -> sync -> frag-reads+MFMA -> sync). Parameter-only deltas from the
// round-7 PASS: BK 64->128 (kk-unroll 4 inside the same barrier pair).
// grid = (8, 8, 4) = 256 blocks -> 1 block/CU. LDS = 52 KB (<64 KB static).
// Block p writes only rows with edge id == p; bias fused in epilogue.
// MFMA k-order identical to round 7 -> bit-identical output.
// ---------------------------------------------------------------------------
__global__ __launch_bounds__(256) void gemm_kernel(
    const unsigned short* __restrict__ FPbf,   // [N][H] bf16
    const unsigned short* __restrict__ Btbf,   // [4][O][H] bf16
    const float* __restrict__ bias,            // [4][O]
    const int* __restrict__ edge_types,        // [N][order]
    const int* __restrict__ msg_to_p, const int* __restrict__ order_p,
    float* __restrict__ out)                   // [N][O]
{
  __shared__ __align__(16) unsigned short Ash[BM][LPAD];
  __shared__ __align__(16) unsigned short Bsh[BO][LPAD];
  const int tid  = threadIdx.x;
  const int lane = tid & 63;
  const int wave = tid >> 6;
  const int wr = wave >> 1, wc = wave & 1;   // 2x2 wave grid: 64-row x 32-col strips
  const int m0 = blockIdx.x * BM, o0 = blockIdx.y * BO;
  const int p  = blockIdx.z;
  const int msg_to = msg_to_p[0];
  const int order  = order_p[0];

  f32x4 acc[4][2];
#pragma unroll
  for (int i = 0; i < 4; ++i)
#pragma unroll
    for (int j = 0; j < 2; ++j) acc[i][j] = (f32x4){0.f, 0.f, 0.f, 0.f};

  const int l15 = lane & 15;
  const int lk0 = (lane >> 4) * 8;   // k-octet base within a 32-wide k-slice

  for (int kt = 0; kt < HH; kt += BK) {
    // stage A (128x128) and B^T (64x128): 256 thr, 8 + 4 chunks of 8 bf16
    // chunk map: row = idx>>4 (16 chunks/row), k8 = (idx&15)*8
#pragma unroll
    for (int c = 0; c < 8; ++c) {
      int idx = c*256 + tid; int row = idx >> 4; int k8 = (idx & 15) * 8;
      u16x8 va = *reinterpret_cast<const u16x8*>(FPbf + (size_t)(m0+row)*HH + kt + k8);
      *reinterpret_cast<u16x8*>(&Ash[row][k8]) = va;
    }
#pragma unroll
    for (int c = 0; c < 4; ++c) {
      int idx = c*256 + tid; int row = idx >> 4; int k8 = (idx & 15) * 8;
      u16x8 vb = *reinterpret_cast<const u16x8*>(Btbf + ((size_t)p*OO + o0 + row)*HH + kt + k8);
      *reinterpret_cast<u16x8*>(&Bsh[row][k8]) = vb;
    }
    __syncthreads();

#pragma unroll
    for (int kk = 0; kk < 4; ++kk) {
      u16x8 bF0 = *reinterpret_cast<const u16x8*>(&Bsh[wc*32 +  0 + l15][kk*32 + lk0]);
      u16x8 bF1 = *reinterpret_cast<const u16x8*>(&Bsh[wc*32 + 16 + l15][kk*32 + lk0]);
      u16x8 aF[4];
#pragma unroll
      for (int mi = 0; mi < 4; ++mi)
        aF[mi] = *reinterpret_cast<const u16x8*>(&Ash[wr*64 + mi*16 + l15][kk*32 + lk0]);
#pragma unroll
      for (int mi = 0; mi < 4; ++mi) {
        asm("v_mfma_f32_16x16x32_bf16 %0, %1, %2, %0"
            : "+v"(acc[mi][0]) : "v"(aF[mi]), "v"(bF0));
        asm("v_mfma_f32_16x16x32_bf16 %0, %1, %2, %0"
            : "+v"(acc[mi][1]) : "v"(aF[mi]), "v"(bF1));
      }
    }

    __syncthreads();
  }

  asm volatile("s_nop 7\n\ts_nop 7" ::: "memory");  // MFMA->VALU hazard insurance

  // epilogue: C/D layout col=lane&15, row=(lane>>4)*4+reg
#pragma unroll
  for (int mi = 0; mi < 4; ++mi) {
#pragma unroll
    for (int r = 0; r < 4; ++r) {
      int n  = m0 + wr*64 + mi*16 + (lane >> 4)*4 + r;
      int id = edge_types[n*order + msg_to];
      if (id != p) continue;
      const int ob = o0 + wc*32 + l15;
#pragma unroll
      for (int ni = 0; ni < 2; ++ni) {
        int o = ob + ni*16;
        out[(size_t)n*OO + o] = acc[mi][ni][r] + bias[p*OO + o];
      }
    }
  }
}

extern "C" void kernel_launch(void* const* d_in, const int* in_sizes, int n_in,
                              void* d_out, int out_size, void* d_ws, size_t ws_size,
                              hipStream_t stream) {
  const float* inp        = (const float*)d_in[0];
  const float* params     = (const float*)d_in[1];
  const float* bias       = (const float*)d_in[2];
  const int*   edge_types = (const int*)d_in[3];
  // d_in[4]=atoms, d_in[5]=atom_edges unused by reference
  const int*   msg_to_p   = (const int*)d_in[6];
  const int*   order_p    = (const int*)d_in[7];
  float* out = (float*)d_out;

  unsigned short* FPbf = (unsigned short*)d_ws;            // N*H bf16 = 1 MB
  unsigned short* Btbf = FPbf + (size_t)NN*HH;             // 4*O*H bf16 = 2 MB

  prep_kernel<<<512, 256, 0, stream>>>(inp, params, msg_to_p, order_p, FPbf, Btbf);
  gemm_kernel<<<dim3(NN/BM, OO/BO, 4), 256, 0, stream>>>(FPbf, Btbf, bias, edge_types,
                                                         msg_to_p, order_p, out);
}